// Round 1
// baseline (663.653 us; speedup 1.0000x reference)
//
#include <hip/hip_runtime.h>
#include <math.h>

// Problem constants (from reference setup_inputs)
constexpr int Bn = 64;      // batch
constexpr int Pn = 24564;   // priors
constexpr int Cn = 21;      // classes
constexpr int Nn = 16;      // truths per image
constexpr float VAR0 = 0.1f, VAR1 = 0.2f, THRv = 0.5f;

__device__ __forceinline__ float iou_tp(float tx1, float ty1, float tx2, float ty2,
                                        float px1, float py1, float px2, float py2) {
  float lx = fmaxf(tx1, px1), ly = fmaxf(ty1, py1);
  float rx = fminf(tx2, px2), ry = fminf(ty2, py2);
  float w = fmaxf(rx - lx, 0.f), h = fmaxf(ry - ly, 0.f);
  float inter = w * h;
  float aa = (tx2 - tx1) * (ty2 - ty1);
  float ab = (px2 - px1) * (py2 - py1);
  return inter / (aa + ab - inter);
}

// ---------------- Kernel A: best prior per truth (argmax over P, first-max tie) --------
__global__ void best_prior_kernel(const float* __restrict__ priors,
                                  const float* __restrict__ truths,
                                  int* __restrict__ bpi) {
  const int b = blockIdx.x;
  const int tid = threadIdx.x;
  __shared__ float4 tru[Nn];
  if (tid < Nn) tru[tid] = reinterpret_cast<const float4*>(truths)[b * Nn + tid];
  __syncthreads();

  float bv[Nn];
  int bi[Nn];
#pragma unroll
  for (int n = 0; n < Nn; n++) { bv[n] = -1.0f; bi[n] = 0; }

  for (int p = tid; p < Pn; p += blockDim.x) {
    float4 pr = reinterpret_cast<const float4*>(priors)[p];
    float px1 = pr.x - pr.z * 0.5f, py1 = pr.y - pr.w * 0.5f;
    float px2 = pr.x + pr.z * 0.5f, py2 = pr.y + pr.w * 0.5f;
#pragma unroll
    for (int n = 0; n < Nn; n++) {
      float v = iou_tp(tru[n].x, tru[n].y, tru[n].z, tru[n].w, px1, py1, px2, py2);
      if (v > bv[n]) { bv[n] = v; bi[n] = p; }   // strict > keeps lowest p within thread stride
    }
  }

  __shared__ float sval[256];
  __shared__ int sidx[256];
  for (int n = 0; n < Nn; n++) {
    sval[tid] = bv[n]; sidx[tid] = bi[n];
    __syncthreads();
    for (int s = 128; s > 0; s >>= 1) {
      if (tid < s) {
        float v2 = sval[tid + s]; int i2 = sidx[tid + s];
        if (v2 > sval[tid] || (v2 == sval[tid] && i2 < sidx[tid])) { sval[tid] = v2; sidx[tid] = i2; }
      }
      __syncthreads();
    }
    if (tid == 0) bpi[b * Nn + n] = sidx[0];
    __syncthreads();
  }
}

// ---------------- Kernel B: match, targets, smooth-L1, CE, lc --------------------------
__global__ void match_loss_kernel(const float* __restrict__ loc,
                                  const float* __restrict__ conf,
                                  const float* __restrict__ priors,
                                  const float* __restrict__ truths,
                                  const int* __restrict__ labels,
                                  const int* __restrict__ bpi,
                                  float* __restrict__ lc_out,
                                  int* __restrict__ num_pos,
                                  float* __restrict__ acc /* [0]=loss_l [1]=ce_pos */) {
  const int b = blockIdx.y;
  const int tid = threadIdx.x;
  const int p = blockIdx.x * blockDim.x + tid;

  __shared__ float4 tru[Nn];
  __shared__ int lab[Nn];
  __shared__ int bp[Nn];
  if (tid < Nn) {
    tru[tid] = reinterpret_cast<const float4*>(truths)[b * Nn + tid];
    lab[tid] = labels[b * Nn + tid];
    bp[tid]  = bpi[b * Nn + tid];
  }
  __syncthreads();

  float my_ll = 0.f, my_cep = 0.f;
  int my_np = 0;

  if (p < Pn) {
    float4 pr = reinterpret_cast<const float4*>(priors)[p];
    float px1 = pr.x - pr.z * 0.5f, py1 = pr.y - pr.w * 0.5f;
    float px2 = pr.x + pr.z * 0.5f, py2 = pr.y + pr.w * 0.5f;

    float best = -1.0f;
    int bidx = 0;
#pragma unroll
    for (int n = 0; n < Nn; n++) {
      float v = iou_tp(tru[n].x, tru[n].y, tru[n].z, tru[n].w, px1, py1, px2, py2);
      if (v > best) { best = v; bidx = n; }      // first-occurrence argmax over axis 0
    }
#pragma unroll
    for (int n = 0; n < Nn; n++) {               // forced matches: ascending n => last wins
      if (bp[n] == p) { best = 2.0f; bidx = n; }
    }

    int conf_t = (best < THRv) ? 0 : (lab[bidx] + 1);
    bool pos = conf_t > 0;

    // logsumexp over 21 classes + gathered logit
    const float* crow = conf + ((size_t)b * Pn + p) * Cn;
    float m = -INFINITY, g = 0.f;
#pragma unroll
    for (int c = 0; c < Cn; c++) {
      float x = crow[c];
      m = fmaxf(m, x);
      if (c == conf_t) g = x;
    }
    float s = 0.f;
#pragma unroll
    for (int c = 0; c < Cn; c++) s += expf(crow[c] - m);
    float lse = m + logf(s);
    float ce = lse - g;

    lc_out[(size_t)b * Pn + p] = pos ? 0.f : ce;

    if (pos) {
      my_np = 1;
      my_cep = ce;
      float4 t = tru[bidx];
      float gx = ((t.x + t.z) * 0.5f - pr.x) / (VAR0 * pr.z);
      float gy = ((t.y + t.w) * 0.5f - pr.y) / (VAR0 * pr.w);
      float gw = logf((t.z - t.x) / pr.z) / VAR1;
      float gh = logf((t.w - t.y) / pr.w) / VAR1;
      const float* lrow = loc + ((size_t)b * Pn + p) * 4;
      float d0 = lrow[0] - gx, d1 = lrow[1] - gy, d2 = lrow[2] - gw, d3 = lrow[3] - gh;
      float a0 = fabsf(d0), a1 = fabsf(d1), a2 = fabsf(d2), a3 = fabsf(d3);
      my_ll  = (a0 < 1.f ? 0.5f * d0 * d0 : a0 - 0.5f);
      my_ll += (a1 < 1.f ? 0.5f * d1 * d1 : a1 - 0.5f);
      my_ll += (a2 < 1.f ? 0.5f * d2 * d2 : a2 - 0.5f);
      my_ll += (a3 < 1.f ? 0.5f * d3 * d3 : a3 - 0.5f);
    }
  }

  // block reduction of (loss_l, ce_pos, num_pos)
  __shared__ float sll[256];
  __shared__ float sce[256];
  __shared__ int snp[256];
  sll[tid] = my_ll; sce[tid] = my_cep; snp[tid] = my_np;
  __syncthreads();
  for (int s2 = 128; s2 > 0; s2 >>= 1) {
    if (tid < s2) {
      sll[tid] += sll[tid + s2];
      sce[tid] += sce[tid + s2];
      snp[tid] += snp[tid + s2];
    }
    __syncthreads();
  }
  if (tid == 0) {
    if (sll[0] != 0.f) atomicAdd(&acc[0], sll[0]);
    if (sce[0] != 0.f) atomicAdd(&acc[1], sce[0]);
    if (snp[0] != 0)   atomicAdd(&num_pos[b], snp[0]);
  }
}

// ---------------- Kernel C: per-batch exact top-K sum via radix select ------------------
__global__ void topk_kernel(const float* __restrict__ lc,
                            const int* __restrict__ num_pos,
                            float* __restrict__ topk) {
  const int b = blockIdx.x;
  const int tid = threadIdx.x;
  const float* row = lc + (size_t)b * Pn;
  const int K = min(3 * num_pos[b], Pn - 1);

  __shared__ unsigned cnt[256];
  __shared__ float bsum[256];
  __shared__ unsigned sh_prefix;
  __shared__ int sh_rem;
  __shared__ float sh_sum;
  __shared__ int sh_done;
  if (tid == 0) { sh_prefix = 0u; sh_rem = K; sh_sum = 0.f; sh_done = (K <= 0) ? 1 : 0; }
  __syncthreads();

  for (int pass = 0; pass < 4; pass++) {
    if (sh_done) break;                  // uniform (shared), safe
    const int shift = 24 - pass * 8;
    cnt[tid] = 0u; bsum[tid] = 0.f;
    __syncthreads();
    const unsigned pref = sh_prefix;
    for (int p = tid; p < Pn; p += 256) {
      float f = row[p];
      unsigned u = __float_as_uint(f);
      u = (u & 0x80000000u) ? ~u : (u | 0x80000000u);
      bool match = (pass == 0) || ((u >> (32 - 8 * pass)) == pref);
      if (match) {
        unsigned bkt = (u >> shift) & 255u;
        atomicAdd(&cnt[bkt], 1u);
        atomicAdd(&bsum[bkt], f);
      }
    }
    __syncthreads();
    if (tid == 0) {
      int rem = sh_rem;
      float ssum = sh_sum;
      unsigned pivot = 0u;
      int done = 0;
      int found = 0;
      for (int bkt = 255; bkt >= 0; bkt--) {
        if ((int)cnt[bkt] <= rem) {
          ssum += bsum[bkt];
          rem -= (int)cnt[bkt];
          if (rem == 0) { done = 1; break; }
        } else {
          pivot = (unsigned)bkt;
          found = 1;
          break;
        }
      }
      if (!done && !found) done = 1;     // safety: nothing left
      if (!done && pass == 3) {
        // full 32-bit key determined; all remaining ties have identical value
        unsigned key = (sh_prefix << 8) | pivot;
        unsigned bits = (key & 0x80000000u) ? (key & 0x7fffffffu) : ~key;
        float f = __uint_as_float(bits);
        ssum += (float)rem * f;
        done = 1;
      }
      sh_prefix = (sh_prefix << 8) | pivot;
      sh_rem = rem;
      sh_sum = ssum;
      sh_done = done;
    }
    __syncthreads();
  }
  if (tid == 0) topk[b] = sh_sum;
}

// ---------------- Kernel D: finalize ----------------------------------------------------
__global__ void finalize_kernel(const int* __restrict__ num_pos,
                                const float* __restrict__ topk,
                                const float* __restrict__ acc,
                                float* __restrict__ out) {
  if (threadIdx.x == 0 && blockIdx.x == 0) {
    int tot = 0;
    float tk = 0.f;
    for (int b = 0; b < Bn; b++) { tot += num_pos[b]; tk += topk[b]; }
    float ftot = (float)tot;
    out[0] = acc[0] / ftot;
    out[1] = (acc[1] + tk) / ftot;
  }
}

extern "C" void kernel_launch(void* const* d_in, const int* in_sizes, int n_in,
                              void* d_out, int out_size, void* d_ws, size_t ws_size,
                              hipStream_t stream) {
  const float* loc    = (const float*)d_in[0];  // [B,P,4]
  const float* conf   = (const float*)d_in[1];  // [B,P,21]
  const float* priors = (const float*)d_in[2];  // [P,4]
  const float* truths = (const float*)d_in[3];  // [B,N,4]
  const int*   labels = (const int*)d_in[4];    // [B,N]
  float* out = (float*)d_out;                   // [2]

  // workspace layout
  float* lc      = (float*)d_ws;                // B*P
  int*   num_pos = (int*)(lc + (size_t)Bn * Pn);// B
  float* topk    = (float*)(num_pos + Bn);      // B
  float* acc     = topk + Bn;                   // 2
  int*   bpi     = (int*)(acc + 2);             // B*N

  // zero the accumulator tail (ws is poisoned 0xAA before every launch)
  size_t zbytes = (size_t)(Bn + Bn + 2 + Bn * Nn) * 4;
  hipMemsetAsync(num_pos, 0, zbytes, stream);

  best_prior_kernel<<<Bn, 256, 0, stream>>>(priors, truths, bpi);

  dim3 gridB((Pn + 255) / 256, Bn);
  match_loss_kernel<<<gridB, 256, 0, stream>>>(loc, conf, priors, truths, labels, bpi,
                                               lc, num_pos, acc);

  topk_kernel<<<Bn, 256, 0, stream>>>(lc, num_pos, topk);

  finalize_kernel<<<1, 64, 0, stream>>>(num_pos, topk, acc, out);
}

// Round 4
// 502.954 us; speedup vs baseline: 1.3195x; 1.3195x over previous
//
#include <hip/hip_runtime.h>
#include <math.h>

// Problem constants (from reference setup_inputs)
constexpr int Bn = 64;      // batch
constexpr int Pn = 24564;   // priors
constexpr int Cn = 21;      // classes
constexpr int Nn = 16;      // truths per image
constexpr int CH = 12;      // prior chunks for best_prior stage 1
constexpr int CHSZ = 2048;  // priors per chunk (12*2048 = 24576 >= 24564)
constexpr float VAR0 = 0.1f, VAR1 = 0.2f, THRv = 0.5f;

__device__ __forceinline__ float iou_tp(float tx1, float ty1, float tx2, float ty2,
                                        float px1, float py1, float px2, float py2) {
  float lx = fmaxf(tx1, px1), ly = fmaxf(ty1, py1);
  float rx = fminf(tx2, px2), ry = fminf(ty2, py2);
  float w = fmaxf(rx - lx, 0.f), h = fmaxf(ry - ly, 0.f);
  float inter = w * h;
  float aa = (tx2 - tx1) * (ty2 - ty1);
  float ab = (px2 - px1) * (py2 - py1);
  return inter / (aa + ab - inter);
}

// ------------- Kernel A1: partial best prior per truth, per (batch, chunk) -------------
__global__ void best_prior_part(const float* __restrict__ priors,
                                const float* __restrict__ truths,
                                float* __restrict__ pbv, int* __restrict__ pbi) {
  const int c = blockIdx.x;
  const int b = blockIdx.y;
  const int tid = threadIdx.x;
  __shared__ float4 tru[Nn];
  if (tid < Nn) tru[tid] = reinterpret_cast<const float4*>(truths)[b * Nn + tid];
  __syncthreads();

  float bv[Nn];
  int bi[Nn];
#pragma unroll
  for (int n = 0; n < Nn; n++) { bv[n] = -1.0f; bi[n] = 0x7fffffff; }

  const int base = c * CHSZ;
#pragma unroll
  for (int j = 0; j < CHSZ / 256; j++) {
    int p = base + j * 256 + tid;          // ascending p within thread -> strict > keeps lowest
    if (p < Pn) {
      float4 pr = reinterpret_cast<const float4*>(priors)[p];
      float px1 = pr.x - pr.z * 0.5f, py1 = pr.y - pr.w * 0.5f;
      float px2 = pr.x + pr.z * 0.5f, py2 = pr.y + pr.w * 0.5f;
#pragma unroll
      for (int n = 0; n < Nn; n++) {
        float v = iou_tp(tru[n].x, tru[n].y, tru[n].z, tru[n].w, px1, py1, px2, py2);
        if (v > bv[n]) { bv[n] = v; bi[n] = p; }
      }
    }
  }

  // wave-level butterfly reduce (64 lanes), tie-break: smaller prior index
  const int lane = tid & 63, wv = tid >> 6;
  __shared__ float swv[4][Nn];
  __shared__ int swi[4][Nn];
#pragma unroll
  for (int n = 0; n < Nn; n++) {
    float v = bv[n]; int i = bi[n];
#pragma unroll
    for (int m = 1; m < 64; m <<= 1) {
      float ov = __shfl_xor(v, m, 64);
      int oi = __shfl_xor(i, m, 64);
      if (ov > v || (ov == v && oi < i)) { v = ov; i = oi; }
    }
    if (lane == 0) { swv[wv][n] = v; swi[wv][n] = i; }
  }
  __syncthreads();
  if (tid < Nn) {
    float v = swv[0][tid]; int i = swi[0][tid];
#pragma unroll
    for (int w = 1; w < 4; w++) {
      float ov = swv[w][tid]; int oi = swi[w][tid];
      if (ov > v || (ov == v && oi < i)) { v = ov; i = oi; }
    }
    pbv[(b * CH + c) * Nn + tid] = v;
    pbi[(b * CH + c) * Nn + tid] = i;
  }
}

// ------------- Kernel A2: merge chunk partials -> best prior per truth ------------------
__global__ void best_prior_merge(const float* __restrict__ pbv,
                                 const int* __restrict__ pbi,
                                 int* __restrict__ bpi) {
  const int b = blockIdx.x;
  const int n = threadIdx.x;
  if (n < Nn) {
    float v = pbv[(b * CH) * Nn + n];
    int i = pbi[(b * CH) * Nn + n];
#pragma unroll
    for (int c = 1; c < CH; c++) {
      float ov = pbv[(b * CH + c) * Nn + n];
      int oi = pbi[(b * CH + c) * Nn + n];
      if (ov > v || (ov == v && oi < i)) { v = ov; i = oi; }
    }
    bpi[b * Nn + n] = i;
  }
}

// ---------------- Kernel B: match, targets, smooth-L1, CE, lc --------------------------
__global__ void match_loss_kernel(const float* __restrict__ loc,
                                  const float* __restrict__ conf,
                                  const float* __restrict__ priors,
                                  const float* __restrict__ truths,
                                  const int* __restrict__ labels,
                                  const int* __restrict__ bpi,
                                  float* __restrict__ lc_out,
                                  int* __restrict__ num_pos,
                                  float* __restrict__ acc /* [0]=loss_l [1]=ce_pos */) {
  const int b = blockIdx.y;
  const int tid = threadIdx.x;
  const int p = blockIdx.x * blockDim.x + tid;

  __shared__ float4 tru[Nn];
  __shared__ int lab[Nn];
  __shared__ int bp[Nn];
  if (tid < Nn) {
    tru[tid] = reinterpret_cast<const float4*>(truths)[b * Nn + tid];
    lab[tid] = labels[b * Nn + tid];
    bp[tid]  = bpi[b * Nn + tid];
  }
  __syncthreads();

  float my_ll = 0.f, my_cep = 0.f;
  int my_np = 0;

  if (p < Pn) {
    float4 pr = reinterpret_cast<const float4*>(priors)[p];
    float px1 = pr.x - pr.z * 0.5f, py1 = pr.y - pr.w * 0.5f;
    float px2 = pr.x + pr.z * 0.5f, py2 = pr.y + pr.w * 0.5f;

    float best = -1.0f;
    int bidx = 0;
#pragma unroll
    for (int n = 0; n < Nn; n++) {
      float v = iou_tp(tru[n].x, tru[n].y, tru[n].z, tru[n].w, px1, py1, px2, py2);
      if (v > best) { best = v; bidx = n; }      // first-occurrence argmax over axis 0
    }
#pragma unroll
    for (int n = 0; n < Nn; n++) {               // forced matches: ascending n => last wins
      if (bp[n] == p) { best = 2.0f; bidx = n; }
    }

    int conf_t = (best < THRv) ? 0 : (lab[bidx] + 1);
    bool pos = conf_t > 0;

    // logsumexp over 21 classes + gathered logit
    const float* crow = conf + ((size_t)b * Pn + p) * Cn;
    float m = -INFINITY;
#pragma unroll
    for (int c = 0; c < Cn; c++) m = fmaxf(m, crow[c]);
    float s = 0.f;
#pragma unroll
    for (int c = 0; c < Cn; c++) s += __expf(crow[c] - m);
    float lse = m + __logf(s);
    float ce = lse - crow[conf_t];

    lc_out[(size_t)b * Pn + p] = pos ? 0.f : ce;

    if (pos) {
      my_np = 1;
      my_cep = ce;
      float4 t = tru[bidx];
      float gx = ((t.x + t.z) * 0.5f - pr.x) / (VAR0 * pr.z);
      float gy = ((t.y + t.w) * 0.5f - pr.y) / (VAR0 * pr.w);
      float gw = __logf((t.z - t.x) / pr.z) / VAR1;
      float gh = __logf((t.w - t.y) / pr.w) / VAR1;
      const float* lrow = loc + ((size_t)b * Pn + p) * 4;
      float d0 = lrow[0] - gx, d1 = lrow[1] - gy, d2 = lrow[2] - gw, d3 = lrow[3] - gh;
      float a0 = fabsf(d0), a1 = fabsf(d1), a2 = fabsf(d2), a3 = fabsf(d3);
      my_ll  = (a0 < 1.f ? 0.5f * d0 * d0 : a0 - 0.5f);
      my_ll += (a1 < 1.f ? 0.5f * d1 * d1 : a1 - 0.5f);
      my_ll += (a2 < 1.f ? 0.5f * d2 * d2 : a2 - 0.5f);
      my_ll += (a3 < 1.f ? 0.5f * d3 * d3 : a3 - 0.5f);
    }
  }

  // block reduction of (loss_l, ce_pos, num_pos)
  __shared__ float sll[256];
  __shared__ float sce[256];
  __shared__ int snp[256];
  sll[tid] = my_ll; sce[tid] = my_cep; snp[tid] = my_np;
  __syncthreads();
  for (int s2 = 128; s2 > 0; s2 >>= 1) {
    if (tid < s2) {
      sll[tid] += sll[tid + s2];
      sce[tid] += sce[tid + s2];
      snp[tid] += snp[tid + s2];
    }
    __syncthreads();
  }
  if (tid == 0) {
    if (sll[0] != 0.f) atomicAdd(&acc[0], sll[0]);
    if (sce[0] != 0.f) atomicAdd(&acc[1], sce[0]);
    if (snp[0] != 0)   atomicAdd(&num_pos[b], snp[0]);
  }
}

// ------------- Kernel C: per-batch exact top-K sum via radix select --------------------
// 1024 threads/block, per-wave histograms (16 waves) to cut hot-bucket atomic serialization.
__global__ __launch_bounds__(1024) void topk_kernel(const float* __restrict__ lc,
                                                    const int* __restrict__ num_pos,
                                                    float* __restrict__ topk) {
  const int b = blockIdx.x;
  const int tid = threadIdx.x;
  const int wv = tid >> 6, lane = tid & 63;
  const float* row = lc + (size_t)b * Pn;
  const int K = min(3 * num_pos[b], Pn - 1);

  __shared__ unsigned cnt[16][256];
  __shared__ float bsum[16][256];
  __shared__ unsigned mcnt[256];
  __shared__ float msum[256];
  __shared__ unsigned sh_prefix;
  __shared__ int sh_rem;
  __shared__ float sh_sum;
  __shared__ int sh_done;
  if (tid == 0) { sh_prefix = 0u; sh_rem = K; sh_sum = 0.f; sh_done = (K <= 0) ? 1 : 0; }
  __syncthreads();

  for (int pass = 0; pass < 4; pass++) {
    if (sh_done) break;                  // uniform (shared), safe
    const int shift = 24 - pass * 8;
    for (int q = lane; q < 256; q += 64) { cnt[wv][q] = 0u; bsum[wv][q] = 0.f; }
    __syncthreads();
    const unsigned pref = sh_prefix;
    for (int p = tid; p < Pn; p += 1024) {
      float f = row[p];
      unsigned u = __float_as_uint(f) | 0x80000000u;   // lc >= 0 always
      bool match = (pass == 0) || ((u >> (32 - 8 * pass)) == pref);
      if (match) {
        unsigned bkt = (u >> shift) & 255u;
        atomicAdd(&cnt[wv][bkt], 1u);
        atomicAdd(&bsum[wv][bkt], f);
      }
    }
    __syncthreads();
    if (tid < 256) {
      unsigned ctot = 0; float stot = 0.f;
#pragma unroll
      for (int w = 0; w < 16; w++) { ctot += cnt[w][tid]; stot += bsum[w][tid]; }
      mcnt[tid] = ctot; msum[tid] = stot;
    }
    __syncthreads();
    if (tid == 0) {
      int rem = sh_rem;
      float ssum = sh_sum;
      unsigned pivot = 0u;
      int done = 0;
      for (int bkt = 255; bkt >= 0; bkt--) {
        unsigned cb = mcnt[bkt];
        if ((int)cb <= rem) {
          ssum += msum[bkt];
          rem -= (int)cb;
          if (rem == 0) { done = 1; break; }
        } else {
          pivot = (unsigned)bkt;
          break;
        }
      }
      if (!done && pass == 3) {
        // full 32-bit key known; remaining ties share the identical value
        unsigned key = (sh_prefix << 8) | pivot;
        float f = __uint_as_float(key & 0x7fffffffu);
        ssum += (float)rem * f;
        done = 1;
      }
      sh_prefix = (sh_prefix << 8) | pivot;
      sh_rem = rem;
      sh_sum = ssum;
      sh_done = done;
    }
    __syncthreads();
  }
  if (tid == 0) topk[b] = sh_sum;
}

// ---------------- Kernel D: finalize ----------------------------------------------------
__global__ void finalize_kernel(const int* __restrict__ num_pos,
                                const float* __restrict__ topk,
                                const float* __restrict__ acc,
                                float* __restrict__ out) {
  if (threadIdx.x == 0 && blockIdx.x == 0) {
    int tot = 0;
    float tk = 0.f;
    for (int b = 0; b < Bn; b++) { tot += num_pos[b]; tk += topk[b]; }
    float ftot = (float)tot;
    out[0] = acc[0] / ftot;
    out[1] = (acc[1] + tk) / ftot;
  }
}

extern "C" void kernel_launch(void* const* d_in, const int* in_sizes, int n_in,
                              void* d_out, int out_size, void* d_ws, size_t ws_size,
                              hipStream_t stream) {
  const float* loc    = (const float*)d_in[0];  // [B,P,4]
  const float* conf   = (const float*)d_in[1];  // [B,P,21]
  const float* priors = (const float*)d_in[2];  // [P,4]
  const float* truths = (const float*)d_in[3];  // [B,N,4]
  const int*   labels = (const int*)d_in[4];    // [B,N]
  float* out = (float*)d_out;                   // [2]

  // workspace layout
  float* lc      = (float*)d_ws;                   // B*P
  int*   num_pos = (int*)(lc + (size_t)Bn * Pn);   // B
  float* topk    = (float*)(num_pos + Bn);         // B
  float* acc     = topk + Bn;                      // 2
  int*   bpi     = (int*)(acc + 2);                // B*N
  float* pbv     = (float*)(bpi + Bn * Nn);        // B*CH*N
  int*   pbi     = (int*)(pbv + Bn * CH * Nn);     // B*CH*N

  // zero the accumulator tail (ws is poisoned 0xAA before every launch)
  size_t zbytes = (size_t)(Bn + Bn + 2 + Bn * Nn) * 4;
  hipMemsetAsync(num_pos, 0, zbytes, stream);

  dim3 gridA(CH, Bn);
  best_prior_part<<<gridA, 256, 0, stream>>>(priors, truths, pbv, pbi);
  best_prior_merge<<<Bn, 64, 0, stream>>>(pbv, pbi, bpi);

  dim3 gridB((Pn + 255) / 256, Bn);
  match_loss_kernel<<<gridB, 256, 0, stream>>>(loc, conf, priors, truths, labels, bpi,
                                               lc, num_pos, acc);

  topk_kernel<<<Bn, 1024, 0, stream>>>(lc, num_pos, topk);

  finalize_kernel<<<1, 64, 0, stream>>>(num_pos, topk, acc, out);
}